// Round 16
// baseline (505.453 us; speedup 1.0000x reference)
//
#include <hip/hip_runtime.h>

// x: (16, 3, 1024, 1024) f32  ->  out: (16, 4, 512, 512) f32
// gray = 0.114*x[:,0] + 0.587*x[:,1] + 0.299*x[:,2]; 2x2 Haar -> 4 planes.
//
// R16 CALIBRATION v2: R15's scrub speed was unknown -> T_cold ambiguous
// (43..71us). This round the scrub is OUR grid-stride float4 copy of
// 384MiB->384MiB in d_ws (~805MB traffic, ~125us) — big enough to enter
// the rocprof top-5 with measured dur+hbm_gbps. T_cold(kernel) =
// dur_us - 287.5 - scrub_dur_measured.

#define B_  16
#define H_  1024
#define W_  1024
#define OH_ 512
#define OW_ 512

__global__ __launch_bounds__(256) void haar_gray_kernel(
    const float* __restrict__ x, float* __restrict__ out)
{
    // one thread = 4 output pixels: 2 at cols [2t,2t+1], 2 at cols [256+2t,...]
    const int tid = blockIdx.x * blockDim.x + threadIdx.x;

    const int b   = tid >> 16;              // batch
    const int rem = tid & 0xFFFF;
    const int i   = rem >> 7;               // output row (0..511)
    const int t   = rem & 127;              // lane-dense col-group index
    const int h0  = i << 1;                 // input row pair

    const float* bp = x + (size_t)b * 3 * H_ * W_;
    const size_t rowT = (size_t)h0 * W_;
    const size_t rowB = rowT + W_;
    const size_t CH = (size_t)H_ * W_;

    const float wb = 0.114f, wg = 0.587f, wr = 0.299f;

    // left quad: input cols [4t, 4t+4) — lane-dense float4 loads
    const int wL = t << 2;
    const float4 L0t = *reinterpret_cast<const float4*>(bp + 0 * CH + rowT + wL);
    const float4 L0b = *reinterpret_cast<const float4*>(bp + 0 * CH + rowB + wL);
    const float4 L1t = *reinterpret_cast<const float4*>(bp + 1 * CH + rowT + wL);
    const float4 L1b = *reinterpret_cast<const float4*>(bp + 1 * CH + rowB + wL);
    const float4 L2t = *reinterpret_cast<const float4*>(bp + 2 * CH + rowT + wL);
    const float4 L2b = *reinterpret_cast<const float4*>(bp + 2 * CH + rowB + wL);

    // right quad: input cols [512+4t, 512+4t+4)
    const int wR = wL + 512;
    const float4 R0t = *reinterpret_cast<const float4*>(bp + 0 * CH + rowT + wR);
    const float4 R0b = *reinterpret_cast<const float4*>(bp + 0 * CH + rowB + wR);
    const float4 R1t = *reinterpret_cast<const float4*>(bp + 1 * CH + rowT + wR);
    const float4 R1b = *reinterpret_cast<const float4*>(bp + 1 * CH + rowB + wR);
    const float4 R2t = *reinterpret_cast<const float4*>(bp + 2 * CH + rowT + wR);
    const float4 R2b = *reinterpret_cast<const float4*>(bp + 2 * CH + rowB + wR);

    // gray
    const float lt0 = fmaf(wb, L0t.x, fmaf(wg, L1t.x, wr * L2t.x));
    const float lt1 = fmaf(wb, L0t.y, fmaf(wg, L1t.y, wr * L2t.y));
    const float lt2 = fmaf(wb, L0t.z, fmaf(wg, L1t.z, wr * L2t.z));
    const float lt3 = fmaf(wb, L0t.w, fmaf(wg, L1t.w, wr * L2t.w));
    const float lb0 = fmaf(wb, L0b.x, fmaf(wg, L1b.x, wr * L2b.x));
    const float lb1 = fmaf(wb, L0b.y, fmaf(wg, L1b.y, wr * L2b.y));
    const float lb2 = fmaf(wb, L0b.z, fmaf(wg, L1b.z, wr * L2b.z));
    const float lb3 = fmaf(wb, L0b.w, fmaf(wg, L1b.w, wr * L2b.w));
    const float rt0 = fmaf(wb, R0t.x, fmaf(wg, R1t.x, wr * R2t.x));
    const float rt1 = fmaf(wb, R0t.y, fmaf(wg, R1t.y, wr * R2t.y));
    const float rt2 = fmaf(wb, R0t.z, fmaf(wg, R1t.z, wr * R2t.z));
    const float rt3 = fmaf(wb, R0t.w, fmaf(wg, R1t.w, wr * R2t.w));
    const float rb0 = fmaf(wb, R0b.x, fmaf(wg, R1b.x, wr * R2b.x));
    const float rb1 = fmaf(wb, R0b.y, fmaf(wg, R1b.y, wr * R2b.y));
    const float rb2 = fmaf(wb, R0b.z, fmaf(wg, R1b.z, wr * R2b.z));
    const float rb3 = fmaf(wb, R0b.w, fmaf(wg, R1b.w, wr * R2b.w));

    // Haar butterfly
    float2 LA, LH, LV, LD, RA, RH, RV, RD;
    {
        const float s_ab = lt0 + lt1, d_ab = lt0 - lt1;
        const float s_cd = lb0 + lb1, d_cd = lb0 - lb1;
        LA.x = (s_ab + s_cd) * 0.5f;  LH.x = (s_ab - s_cd) * 0.5f;
        LV.x = (d_ab + d_cd) * 0.5f;  LD.x = (d_ab - d_cd) * 0.5f;
    }
    {
        const float s_ab = lt2 + lt3, d_ab = lt2 - lt3;
        const float s_cd = lb2 + lb3, d_cd = lb2 - lb3;
        LA.y = (s_ab + s_cd) * 0.5f;  LH.y = (s_ab - s_cd) * 0.5f;
        LV.y = (d_ab + d_cd) * 0.5f;  LD.y = (d_ab - d_cd) * 0.5f;
    }
    {
        const float s_ab = rt0 + rt1, d_ab = rt0 - rt1;
        const float s_cd = rb0 + rb1, d_cd = rb0 - rb1;
        RA.x = (s_ab + s_cd) * 0.5f;  RH.x = (s_ab - s_cd) * 0.5f;
        RV.x = (d_ab + d_cd) * 0.5f;  RD.x = (d_ab - d_cd) * 0.5f;
    }
    {
        const float s_ab = rt2 + rt3, d_ab = rt2 - rt3;
        const float s_cd = rb2 + rb3, d_cd = rb2 - rb3;
        RA.y = (s_ab + s_cd) * 0.5f;  RH.y = (s_ab - s_cd) * 0.5f;
        RV.y = (d_ab + d_cd) * 0.5f;  RD.y = (d_ab - d_cd) * 0.5f;
    }

    // stores: 8 x float2, lane-dense
    const size_t PL = (size_t)OH_ * OW_;
    float* opL = out + ((size_t)b * 4) * PL + (size_t)i * OW_ + (t << 1);
    float* opR = opL + 256;
    *reinterpret_cast<float2*>(opL + 0 * PL) = LA;
    *reinterpret_cast<float2*>(opR + 0 * PL) = RA;
    *reinterpret_cast<float2*>(opL + 1 * PL) = LH;
    *reinterpret_cast<float2*>(opR + 1 * PL) = RH;
    *reinterpret_cast<float2*>(opL + 2 * PL) = LV;
    *reinterpret_cast<float2*>(opR + 2 * PL) = RV;
    *reinterpret_cast<float2*>(opL + 3 * PL) = LD;
    *reinterpret_cast<float2*>(opR + 3 * PL) = RD;
}

// measured L3-scrub: copy 384 MiB -> 384 MiB inside d_ws (~805 MB traffic),
// big enough (~125us) to appear in rocprof top-5 with its own hbm_gbps.
__global__ __launch_bounds__(256) void scrub_copy(
    const float4* __restrict__ src, float4* __restrict__ dst, int n)
{
    const int stride = gridDim.x * blockDim.x;
    for (int k = blockIdx.x * blockDim.x + threadIdx.x; k < n; k += stride)
        dst[k] = src[k];
}

extern "C" void kernel_launch(void* const* d_in, const int* in_sizes, int n_in,
                              void* d_out, int out_size, void* d_ws, size_t ws_size,
                              hipStream_t stream) {
    const float* x = (const float*)d_in[0];
    float* out = (float*)d_out;

    const int total_threads = B_ * OH_ * 128;  // 1,048,576
    const int block = 256;
    const int grid = total_threads / block;    // 4096

    // launch 1 (same conditions as R14's single launch)
    haar_gray_kernel<<<grid, block, 0, stream>>>(x, out);

    // measured scrub: evicts all of L3 (768 MiB traffic footprint)
    const size_t HALF = (size_t)384 << 20;
    if (ws_size >= 2 * HALF) {
        const int n = (int)(HALF / sizeof(float4));   // 25,165,824
        scrub_copy<<<2048, 256, 0, stream>>>(
            (const float4*)d_ws, (float4*)((char*)d_ws + HALF), n);
    }

    // launch 2: L3-cold kernel sample; identical outputs.
    haar_gray_kernel<<<grid, block, 0, stream>>>(x, out);
}

// Round 17
// 467.806 us; speedup vs baseline: 1.0805x; 1.0805x over previous
//
#include <hip/hip_runtime.h>

// x: (16, 3, 1024, 1024) f32  ->  out: (16, 4, 512, 512) f32
// gray-BGR + 2x2 Haar -> 4 planes. Main kernel identical to R14.
//
// R17 ABLATION: R16 measured T_cold ~= 61us (4.4 TB/s) vs 43us roofline.
// This round replaces the scrub with read_probe: loads-only replay of the
// kernel's exact 12-stream float4 pattern over the 768MiB ws (4x input
// span; also evicts L3). It lands in rocprof top-5 with measured BW.
// Decides: read-pattern wall (~4.5 TB/s) vs write-path deficit (>=6 TB/s).

#define B_  16
#define H_  1024
#define W_  1024
#define OH_ 512
#define OW_ 512

__global__ __launch_bounds__(256) void haar_gray_kernel(
    const float* __restrict__ x, float* __restrict__ out)
{
    const int tid = blockIdx.x * blockDim.x + threadIdx.x;

    const int b   = tid >> 16;              // batch
    const int rem = tid & 0xFFFF;
    const int i   = rem >> 7;               // output row (0..511)
    const int t   = rem & 127;              // lane-dense col-group index
    const int h0  = i << 1;                 // input row pair

    const float* bp = x + (size_t)b * 3 * H_ * W_;
    const size_t rowT = (size_t)h0 * W_;
    const size_t rowB = rowT + W_;
    const size_t CH = (size_t)H_ * W_;

    const float wb = 0.114f, wg = 0.587f, wr = 0.299f;

    const int wL = t << 2;
    const float4 L0t = *reinterpret_cast<const float4*>(bp + 0 * CH + rowT + wL);
    const float4 L0b = *reinterpret_cast<const float4*>(bp + 0 * CH + rowB + wL);
    const float4 L1t = *reinterpret_cast<const float4*>(bp + 1 * CH + rowT + wL);
    const float4 L1b = *reinterpret_cast<const float4*>(bp + 1 * CH + rowB + wL);
    const float4 L2t = *reinterpret_cast<const float4*>(bp + 2 * CH + rowT + wL);
    const float4 L2b = *reinterpret_cast<const float4*>(bp + 2 * CH + rowB + wL);

    const int wR = wL + 512;
    const float4 R0t = *reinterpret_cast<const float4*>(bp + 0 * CH + rowT + wR);
    const float4 R0b = *reinterpret_cast<const float4*>(bp + 0 * CH + rowB + wR);
    const float4 R1t = *reinterpret_cast<const float4*>(bp + 1 * CH + rowT + wR);
    const float4 R1b = *reinterpret_cast<const float4*>(bp + 1 * CH + rowB + wR);
    const float4 R2t = *reinterpret_cast<const float4*>(bp + 2 * CH + rowT + wR);
    const float4 R2b = *reinterpret_cast<const float4*>(bp + 2 * CH + rowB + wR);

    const float lt0 = fmaf(wb, L0t.x, fmaf(wg, L1t.x, wr * L2t.x));
    const float lt1 = fmaf(wb, L0t.y, fmaf(wg, L1t.y, wr * L2t.y));
    const float lt2 = fmaf(wb, L0t.z, fmaf(wg, L1t.z, wr * L2t.z));
    const float lt3 = fmaf(wb, L0t.w, fmaf(wg, L1t.w, wr * L2t.w));
    const float lb0 = fmaf(wb, L0b.x, fmaf(wg, L1b.x, wr * L2b.x));
    const float lb1 = fmaf(wb, L0b.y, fmaf(wg, L1b.y, wr * L2b.y));
    const float lb2 = fmaf(wb, L0b.z, fmaf(wg, L1b.z, wr * L2b.z));
    const float lb3 = fmaf(wb, L0b.w, fmaf(wg, L1b.w, wr * L2b.w));
    const float rt0 = fmaf(wb, R0t.x, fmaf(wg, R1t.x, wr * R2t.x));
    const float rt1 = fmaf(wb, R0t.y, fmaf(wg, R1t.y, wr * R2t.y));
    const float rt2 = fmaf(wb, R0t.z, fmaf(wg, R1t.z, wr * R2t.z));
    const float rt3 = fmaf(wb, R0t.w, fmaf(wg, R1t.w, wr * R2t.w));
    const float rb0 = fmaf(wb, R0b.x, fmaf(wg, R1b.x, wr * R2b.x));
    const float rb1 = fmaf(wb, R0b.y, fmaf(wg, R1b.y, wr * R2b.y));
    const float rb2 = fmaf(wb, R0b.z, fmaf(wg, R1b.z, wr * R2b.z));
    const float rb3 = fmaf(wb, R0b.w, fmaf(wg, R1b.w, wr * R2b.w));

    float2 LA, LH, LV, LD, RA, RH, RV, RD;
    {
        const float s_ab = lt0 + lt1, d_ab = lt0 - lt1;
        const float s_cd = lb0 + lb1, d_cd = lb0 - lb1;
        LA.x = (s_ab + s_cd) * 0.5f;  LH.x = (s_ab - s_cd) * 0.5f;
        LV.x = (d_ab + d_cd) * 0.5f;  LD.x = (d_ab - d_cd) * 0.5f;
    }
    {
        const float s_ab = lt2 + lt3, d_ab = lt2 - lt3;
        const float s_cd = lb2 + lb3, d_cd = lb2 - lb3;
        LA.y = (s_ab + s_cd) * 0.5f;  LH.y = (s_ab - s_cd) * 0.5f;
        LV.y = (d_ab + d_cd) * 0.5f;  LD.y = (d_ab - d_cd) * 0.5f;
    }
    {
        const float s_ab = rt0 + rt1, d_ab = rt0 - rt1;
        const float s_cd = rb0 + rb1, d_cd = rb0 - rb1;
        RA.x = (s_ab + s_cd) * 0.5f;  RH.x = (s_ab - s_cd) * 0.5f;
        RV.x = (d_ab + d_cd) * 0.5f;  RD.x = (d_ab - d_cd) * 0.5f;
    }
    {
        const float s_ab = rt2 + rt3, d_ab = rt2 - rt3;
        const float s_cd = rb2 + rb3, d_cd = rb2 - rb3;
        RA.y = (s_ab + s_cd) * 0.5f;  RH.y = (s_ab - s_cd) * 0.5f;
        RV.y = (d_ab + d_cd) * 0.5f;  RD.y = (d_ab - d_cd) * 0.5f;
    }

    const size_t PL = (size_t)OH_ * OW_;
    float* opL = out + ((size_t)b * 4) * PL + (size_t)i * OW_ + (t << 1);
    float* opR = opL + 256;
    *reinterpret_cast<float2*>(opL + 0 * PL) = LA;
    *reinterpret_cast<float2*>(opR + 0 * PL) = RA;
    *reinterpret_cast<float2*>(opL + 1 * PL) = LH;
    *reinterpret_cast<float2*>(opR + 1 * PL) = RH;
    *reinterpret_cast<float2*>(opL + 2 * PL) = LV;
    *reinterpret_cast<float2*>(opR + 2 * PL) = RV;
    *reinterpret_cast<float2*>(opL + 3 * PL) = LD;
    *reinterpret_cast<float2*>(opR + 3 * PL) = RD;
}

// loads-only replay of the main kernel's 12-stream pattern over 768 MiB of
// d_ws (64 pseudo-batches of 3x1024x1024). Also serves as the L3 scrub.
__global__ __launch_bounds__(256) void read_probe(const float* __restrict__ w)
{
    const int tid = blockIdx.x * blockDim.x + threadIdx.x;
    const int b   = tid >> 16;              // 0..63
    const int rem = tid & 0xFFFF;
    const int i   = rem >> 7;
    const int t   = rem & 127;
    const int h0  = i << 1;

    const float* bp = w + (size_t)b * 3 * H_ * W_;
    const size_t rowT = (size_t)h0 * W_;
    const size_t rowB = rowT + W_;
    const size_t CH = (size_t)H_ * W_;
    const int wL = t << 2;
    const int wR = wL + 512;

    float4 acc = make_float4(0.f, 0.f, 0.f, 0.f);
#define RD_(off) { const float4 v = *reinterpret_cast<const float4*>(bp + (off)); \
                   acc.x += v.x; acc.y += v.y; acc.z += v.z; acc.w += v.w; }
    RD_(0 * CH + rowT + wL) RD_(0 * CH + rowB + wL)
    RD_(1 * CH + rowT + wL) RD_(1 * CH + rowB + wL)
    RD_(2 * CH + rowT + wL) RD_(2 * CH + rowB + wL)
    RD_(0 * CH + rowT + wR) RD_(0 * CH + rowB + wR)
    RD_(1 * CH + rowT + wR) RD_(1 * CH + rowB + wR)
    RD_(2 * CH + rowT + wR) RD_(2 * CH + rowB + wR)
#undef RD_
    // keep loads live without any store (rule #17)
    asm volatile("" :: "v"(acc.x), "v"(acc.y), "v"(acc.z), "v"(acc.w));
}

extern "C" void kernel_launch(void* const* d_in, const int* in_sizes, int n_in,
                              void* d_out, int out_size, void* d_ws, size_t ws_size,
                              hipStream_t stream) {
    const float* x = (const float*)d_in[0];
    float* out = (float*)d_out;

    const int total_threads = B_ * OH_ * 128;  // 1,048,576
    const int block = 256;
    const int grid = total_threads / block;    // 4096

    // launch 1 (same conditions as R14's single launch)
    haar_gray_kernel<<<grid, block, 0, stream>>>(x, out);

    // read ablation probe over 768 MiB of ws (also evicts L3)
    if (ws_size >= ((size_t)768 << 20)) {
        const int probe_grid = (64 * 512 * 128) / 256;   // 16384 blocks
        read_probe<<<probe_grid, block, 0, stream>>>((const float*)d_ws);
    }

    // launch 2: L3-cold kernel sample; identical outputs.
    haar_gray_kernel<<<grid, block, 0, stream>>>(x, out);
}